// Round 3
// baseline (1914.112 us; speedup 1.0000x reference)
//
#include <hip/hip_runtime.h>

#define N_ATOMS 200000
#define N_EDGES 800000
#define FDIM    133
#define HID     256
#define NMOLS   8000
#define CAP     32   // Poisson(4) degree; P(deg>=32) ~ 1e-20 -> effectively never overflows

typedef unsigned short bf16_t;

__device__ inline float bf2f(bf16_t u) {
    union { unsigned int i; float f; } v; v.i = ((unsigned int)u) << 16; return v.f;
}
__device__ inline bf16_t f2bf(float f) {
    union { float f; unsigned int i; } v; v.f = f;
    return (bf16_t)((v.i + 0x7fffu + ((v.i >> 16) & 1u)) >> 16);   // RNE
}

// dtype-generic element access (all math in fp32)
__device__ inline float ldf(const float* p)  { return *p; }
__device__ inline float ldf(const bf16_t* p) { return bf2f(*p); }
__device__ inline float4 ld4(const float* p) { return *(const float4*)p; }
__device__ inline float4 ld4(const bf16_t* p) {
    ushort4 u = *(const ushort4*)p;
    return make_float4(bf2f(u.x), bf2f(u.y), bf2f(u.z), bf2f(u.w));
}
__device__ inline void st4(float* p, float4 v) { *(float4*)p = v; }
__device__ inline void st4(bf16_t* p, float4 v) {
    ushort4 u; u.x = f2bf(v.x); u.y = f2bf(v.y); u.z = f2bf(v.z); u.w = f2bf(v.w);
    *(ushort4*)p = u;
}

// ---------------- adjacency build (by target); edge_index is int32 from the harness ----------------
__global__ __launch_bounds__(256) void build_adj(const int* __restrict__ ei,
                                                 int* __restrict__ cnt,
                                                 int* __restrict__ lst) {
    int e = blockIdx.x * 256 + threadIdx.x;
    if (e >= N_EDGES) return;
    int s = ei[e];
    int t = ei[N_EDGES + e];
    int p = atomicAdd(&cnt[t], 1);
    if (p < CAP) lst[t * CAP + p] = s;
}

// ---------------- fp32 tiled GEMM: H[M x 256] = A[M x K] @ W[K x 256] ----------------
// 64x64 tile per 256-thread block, BK=16, 4x4 outputs/thread.
template <typename TA, typename TO>
__global__ __launch_bounds__(256) void gemm_xw(const TA* __restrict__ A,
                                               const float* __restrict__ W,
                                               TO* __restrict__ H, int K) {
    __shared__ float As[16][65];
    __shared__ float Bs[16][65];
    const int tid = threadIdx.x;
    const int tx = tid & 15;
    const int ty = tid >> 4;
    const int row0 = blockIdx.x * 64;
    const int col0 = blockIdx.y * 64;

    float acc[4][4] = {};

    for (int k0 = 0; k0 < K; k0 += 16) {
        for (int i = tid; i < 64 * 16; i += 256) {
            int r = i >> 4, c = i & 15;
            int gc = k0 + c;
            As[c][r] = (gc < K) ? ldf(&A[(long long)(row0 + r) * K + gc]) : 0.f;
        }
        for (int i = tid; i < 16 * 64; i += 256) {
            int r = i >> 6, c = i & 63;
            int gr = k0 + r;
            Bs[r][c] = (gr < K) ? W[gr * HID + col0 + c] : 0.f;
        }
        __syncthreads();
        #pragma unroll
        for (int k = 0; k < 16; ++k) {
            float a[4], b[4];
            #pragma unroll
            for (int i = 0; i < 4; ++i) a[i] = As[k][ty * 4 + i];
            #pragma unroll
            for (int j = 0; j < 4; ++j) b[j] = Bs[k][tx * 4 + j];
            #pragma unroll
            for (int i = 0; i < 4; ++i)
                #pragma unroll
                for (int j = 0; j < 4; ++j)
                    acc[i][j] += a[i] * b[j];
        }
        __syncthreads();
    }
    #pragma unroll
    for (int i = 0; i < 4; ++i) {
        int r = row0 + ty * 4 + i;
        st4(&H[(long long)r * HID + col0 + tx * 4],
            make_float4(acc[i][0], acc[i][1], acc[i][2], acc[i][3]));
    }
}

// ---------------- per-atom attention dots: ss = h.a[0:256], st = h.a[256:512] ----------------
template <typename TX>
__global__ __launch_bounds__(256) void dots_kernel(const TX* __restrict__ H,
                                                   const float* __restrict__ a,
                                                   float* __restrict__ ss,
                                                   float* __restrict__ st) {
    int wave = threadIdx.x >> 6;
    int lane = threadIdx.x & 63;
    int atom = blockIdx.x * 4 + wave;
    if (atom >= N_ATOMS) return;
    float4 h4  = ld4(&H[(long long)atom * HID + lane * 4]);
    float4 as4 = ld4(&a[lane * 4]);
    float4 at4 = ld4(&a[HID + lane * 4]);
    float ps = h4.x * as4.x + h4.y * as4.y + h4.z * as4.z + h4.w * as4.w;
    float pt = h4.x * at4.x + h4.y * at4.y + h4.z * at4.z + h4.w * at4.w;
    #pragma unroll
    for (int o = 32; o > 0; o >>= 1) {
        ps += __shfl_xor(ps, o);
        pt += __shfl_xor(pt, o);
    }
    if (lane == 0) { ss[atom] = ps; st[atom] = pt; }
}

// ---------------- fused softmax-aggregate + residual + ELU (one wave per target) ----------------
// X row t is read (residual) only by the wave that writes row t -> safe in-place.
template <typename TX>
__global__ __launch_bounds__(256) void aggregate(const TX* __restrict__ H,
                                                 const float* __restrict__ ss,
                                                 const float* __restrict__ st,
                                                 const int* __restrict__ cnt,
                                                 const int* __restrict__ lst,
                                                 TX* __restrict__ X,
                                                 int residual) {
    int wave = threadIdx.x >> 6;
    int lane = threadIdx.x & 63;
    int t = blockIdx.x * 4 + wave;
    if (t >= N_ATOMS) return;
    int n = cnt[t]; if (n > CAP) n = CAP;
    float stt = st[t];
    float ax = 0.f, ay = 0.f, az = 0.f, aw = 0.f;
    float denom = 0.f;
    for (int i = 0; i < n; ++i) {
        int s = lst[t * CAP + i];
        float e = ss[s] + stt;
        e = e > 0.f ? e : 0.2f * e;            // leaky_relu(0.2)
        float att = __expf(e);
        denom += att;
        float4 hv = ld4(&H[(long long)s * HID + lane * 4]);
        ax += att * hv.x; ay += att * hv.y; az += att * hv.z; aw += att * hv.w;
    }
    float inv = 1.f / (denom + 1e-8f);
    float rx = ax * inv, ry = ay * inv, rz = az * inv, rw = aw * inv;
    if (residual) {
        float4 xv = ld4(&X[(long long)t * HID + lane * 4]);
        rx += xv.x; ry += xv.y; rz += xv.z; rw += xv.w;
    }
    rx = rx > 0.f ? rx : (__expf(rx) - 1.f);   // elu(alpha=1)
    ry = ry > 0.f ? ry : (__expf(ry) - 1.f);
    rz = rz > 0.f ? rz : (__expf(rz) - 1.f);
    rw = rw > 0.f ? rw : (__expf(rw) - 1.f);
    st4(&X[(long long)t * HID + lane * 4], make_float4(rx, ry, rz, rw));
}

// ---------------- molecule mean pool (mol_ids is int32, sorted) ----------------
__device__ inline int lower_bound_i(const int* a, int n, int v) {
    int lo = 0, hi = n;
    while (lo < hi) { int mid = (lo + hi) >> 1; if (a[mid] < v) lo = mid + 1; else hi = mid; }
    return lo;
}

template <typename TX>
__global__ __launch_bounds__(64) void pool_kernel(const TX* __restrict__ X,
                                                  const int* __restrict__ mol,
                                                  float* __restrict__ out) {
    int m = blockIdx.x;
    int lane = threadIdx.x;
    int lo = lower_bound_i(mol, N_ATOMS, m);
    int hi = lower_bound_i(mol, N_ATOMS, m + 1);
    float ax = 0.f, ay = 0.f, az = 0.f, aw = 0.f;
    for (int i = lo; i < hi; ++i) {
        float4 v = ld4(&X[(long long)i * HID + lane * 4]);
        ax += v.x; ay += v.y; az += v.z; aw += v.w;
    }
    float c = (float)(hi - lo);
    float4 r = make_float4(0.f, 0.f, 0.f, 0.f);
    if (c > 0.f) {
        float inv = 1.f / c;
        r = make_float4(ax * inv, ay * inv, az * inv, aw * inv);
    }
    st4(&out[(long long)m * HID + lane * 4], r);
}

// ---------------- driver, templated on hidden-state storage type ----------------
template <typename TX>
static void run_pipeline(const float* f_atoms, const int* ei, const int* mol,
                         const float* W0, const float* a0, const float* W1, const float* a1,
                         const float* W2, const float* a2, float* out,
                         char* ws, hipStream_t stream) {
    size_t off = 0;
    TX* X  = (TX*)(ws + off); off += (size_t)N_ATOMS * HID * sizeof(TX);
    TX* Hb = (TX*)(ws + off); off += (size_t)N_ATOMS * HID * sizeof(TX);
    float* ss = (float*)(ws + off); off += (size_t)N_ATOMS * 4;
    float* st = (float*)(ws + off); off += (size_t)N_ATOMS * 4;
    int* cnt  = (int*)(ws + off);   off += (size_t)N_ATOMS * 4;
    int* lst  = (int*)(ws + off);   off += (size_t)N_ATOMS * CAP * 4;

    hipMemsetAsync(cnt, 0, (size_t)N_ATOMS * 4, stream);
    build_adj<<<(N_EDGES + 255) / 256, 256, 0, stream>>>(ei, cnt, lst);

    const dim3 gemm_grid(N_ATOMS / 64, HID / 64);
    const int  agg_blocks = N_ATOMS / 4;

    // layer 0 (A = f_atoms fp32, K=133, no residual)
    gemm_xw<float, TX><<<gemm_grid, 256, 0, stream>>>(f_atoms, W0, Hb, FDIM);
    dots_kernel<TX><<<agg_blocks, 256, 0, stream>>>(Hb, a0, ss, st);
    aggregate<TX><<<agg_blocks, 256, 0, stream>>>(Hb, ss, st, cnt, lst, X, 0);
    // layer 1
    gemm_xw<TX, TX><<<gemm_grid, 256, 0, stream>>>(X, W1, Hb, HID);
    dots_kernel<TX><<<agg_blocks, 256, 0, stream>>>(Hb, a1, ss, st);
    aggregate<TX><<<agg_blocks, 256, 0, stream>>>(Hb, ss, st, cnt, lst, X, 1);
    // layer 2
    gemm_xw<TX, TX><<<gemm_grid, 256, 0, stream>>>(X, W2, Hb, HID);
    dots_kernel<TX><<<agg_blocks, 256, 0, stream>>>(Hb, a2, ss, st);
    aggregate<TX><<<agg_blocks, 256, 0, stream>>>(Hb, ss, st, cnt, lst, X, 1);

    pool_kernel<TX><<<NMOLS, 64, 0, stream>>>(X, mol, out);
}

extern "C" void kernel_launch(void* const* d_in, const int* in_sizes, int n_in,
                              void* d_out, int out_size, void* d_ws, size_t ws_size,
                              hipStream_t stream) {
    const float* f_atoms = (const float*)d_in[0];
    const int*   ei      = (const int*)d_in[1];    // harness passes integers as int32
    const int*   mol     = (const int*)d_in[2];
    const float* W0      = (const float*)d_in[3];
    const float* a0      = (const float*)d_in[4];
    const float* W1      = (const float*)d_in[5];
    const float* a1      = (const float*)d_in[6];
    const float* W2      = (const float*)d_in[7];
    const float* a2      = (const float*)d_in[8];
    float* out = (float*)d_out;

    const size_t small = (size_t)N_ATOMS * 4 * 3 + (size_t)N_ATOMS * CAP * 4; // ss+st+cnt+lst
    const size_t need_f32  = (size_t)N_ATOMS * HID * 4 * 2 + small;  // ~437.6 MB
    const size_t need_bf16 = (size_t)N_ATOMS * HID * 2 * 2 + small;  // ~232.8 MB

    if (ws_size >= need_f32) {
        run_pipeline<float>(f_atoms, ei, mol, W0, a0, W1, a1, W2, a2, out, (char*)d_ws, stream);
    } else if (ws_size >= need_bf16) {
        run_pipeline<bf16_t>(f_atoms, ei, mol, W0, a0, W1, a1, W2, a2, out, (char*)d_ws, stream);
    }
    // else: workspace too small -> leave output (diagnostic: absmax ~= 1.297, no crash)
}

// Round 4
// 758.734 us; speedup vs baseline: 2.5228x; 2.5228x over previous
//
#include <hip/hip_runtime.h>

#define N_ATOMS 200000
#define N_EDGES 800000
#define FDIM    133
#define HID     256
#define NMOLS   8000
#define CAP     32   // Poisson(4) in-degree; P(deg>=32) ~ 1e-20

typedef unsigned short bf16_t;
typedef __attribute__((ext_vector_type(4))) float f32x4;
typedef __attribute__((ext_vector_type(8))) short bf16x8;

__device__ inline float bf2f(bf16_t u) {
    union { unsigned int i; float f; } v; v.i = ((unsigned int)u) << 16; return v.f;
}
__device__ inline bf16_t f2bf(float f) {
    union { float f; unsigned int i; } v; v.f = f;
    return (bf16_t)((v.i + 0x7fffu + ((v.i >> 16) & 1u)) >> 16);   // RNE
}
__device__ inline float4 ld4(const bf16_t* p) {
    ushort4 u = *(const ushort4*)p;
    return make_float4(bf2f(u.x), bf2f(u.y), bf2f(u.z), bf2f(u.w));
}
__device__ inline void st4(bf16_t* p, float4 v) {
    ushort4 u; u.x = f2bf(v.x); u.y = f2bf(v.y); u.z = f2bf(v.z); u.w = f2bf(v.w);
    *(ushort4*)p = u;
}

// async global->LDS, 16B per lane; lds dest must be wave-uniform base (+lane*16 implicit)
__device__ inline void gload_lds16(const void* g, void* l) {
    __builtin_amdgcn_global_load_lds((const __attribute__((address_space(1))) unsigned int*)g,
                                     (__attribute__((address_space(3))) unsigned int*)l,
                                     16, 0, 0);
}

// ---------------- adjacency build (edge_index arrives as int32) ----------------
__global__ __launch_bounds__(256) void build_adj(const int* __restrict__ ei,
                                                 int* __restrict__ cnt,
                                                 int* __restrict__ lst) {
    int e = blockIdx.x * 256 + threadIdx.x;
    if (e >= N_EDGES) return;
    int s = ei[e];
    int t = ei[N_EDGES + e];
    int p = atomicAdd(&cnt[t], 1);
    if (p < CAP) lst[t * CAP + p] = s;
}

// ---------------- weight transpose+convert: Wt[n][k] = bf16(W[k][n]), zero-pad k>=K ----------------
__global__ __launch_bounds__(256) void transpose_w(const float* __restrict__ W,
                                                   bf16_t* __restrict__ Wt,
                                                   int K, int Kpad) {
    int idx = blockIdx.x * 256 + threadIdx.x;
    if (idx >= HID * Kpad) return;
    int n = idx / Kpad, k = idx - n * Kpad;
    Wt[idx] = (k < K) ? f2bf(W[k * HID + n]) : (bf16_t)0;
}

// ---------------- MFMA GEMM: H[M x 256] = A[M x K] @ W, W given transposed bf16 Wt[256][Kpad] ----
// 128x128 tile, 4 waves (2x2), BK=32, mfma_f32_16x16x32_bf16, 4x4 frags/wave.
template <bool A_FP32, int KSTEPS, int LDA>
__global__ __launch_bounds__(256) void gemm_mfma(const void* __restrict__ Av,
                                                 const bf16_t* __restrict__ Wt,
                                                 bf16_t* __restrict__ H) {
    __shared__ bf16_t As[128][32];   // 8KB, row-major, k contiguous
    __shared__ bf16_t Bs[128][32];   // 8KB, Bs[n][k]
    const int tid  = threadIdx.x;
    const int lane = tid & 63;
    const int w    = tid >> 6;       // wave 0..3
    const int wr   = w >> 1, wc = w & 1;
    const int row0 = blockIdx.x * 128;
    const int n0   = blockIdx.y * 128;
    const int KP   = KSTEPS * 32;    // Wt leading dim

    f32x4 acc[4][4] = {};

    #pragma unroll
    for (int ks = 0; ks < KSTEPS; ++ks) {
        const int k0 = ks * 32;
        if (ks) __syncthreads();     // previous compute done before LDS overwrite

        // ---- stage A tile (128 x 32 bf16 = 8KB) ----
        if constexpr (A_FP32) {
            const float* A = (const float*)Av;
            int r  = tid >> 1;
            int kh = (tid & 1) * 16;
            int grow = row0 + r; if (grow >= N_ATOMS) grow = N_ATOMS - 1;
            const float* src = A + (long long)grow * LDA + k0 + kh;
            short v[16];
            #pragma unroll
            for (int j = 0; j < 16; ++j) {
                int gk = k0 + kh + j;
                v[j] = (gk < LDA) ? (short)f2bf(src[j]) : (short)0;
            }
            *(bf16x8*)&As[r][kh]     = *(bf16x8*)&v[0];
            *(bf16x8*)&As[r][kh + 8] = *(bf16x8*)&v[8];
        } else {
            const bf16_t* A = (const bf16_t*)Av;
            #pragma unroll
            for (int j = 0; j < 2; ++j) {
                int u  = j * 4096 + w * 1024 + lane * 16;  // byte offset in tile
                int r  = u >> 6;                            // 64B per row
                int cb = u & 63;
                int grow = row0 + r; if (grow >= N_ATOMS) grow = N_ATOMS - 1;
                const bf16_t* src = A + (long long)grow * LDA + k0 + (cb >> 1);
                gload_lds16(src, (char*)&As[0][0] + j * 4096 + w * 1024);
            }
        }
        // ---- stage B tile (128 x 32 bf16 = 8KB) from Wt[n][k] ----
        #pragma unroll
        for (int j = 0; j < 2; ++j) {
            int u  = j * 4096 + w * 1024 + lane * 16;
            int r  = u >> 6;
            int cb = u & 63;
            const bf16_t* src = Wt + (long long)(n0 + r) * KP + k0 + (cb >> 1);
            gload_lds16(src, (char*)&Bs[0][0] + j * 4096 + w * 1024);
        }
        __syncthreads();             // staging (incl. vmcnt drain) before frag reads

        // ---- fragments + MFMA ----
        const int fr   = lane & 15;
        const int koff = (lane >> 4) * 8;
        bf16x8 af[4], bfr[4];
        #pragma unroll
        for (int i = 0; i < 4; ++i)
            af[i] = *(const bf16x8*)&As[wr * 64 + i * 16 + fr][koff];
        #pragma unroll
        for (int jn = 0; jn < 4; ++jn)
            bfr[jn] = *(const bf16x8*)&Bs[wc * 64 + jn * 16 + fr][koff];
        #pragma unroll
        for (int i = 0; i < 4; ++i)
            #pragma unroll
            for (int jn = 0; jn < 4; ++jn)
                acc[i][jn] = __builtin_amdgcn_mfma_f32_16x16x32_bf16(af[i], bfr[jn], acc[i][jn], 0, 0, 0);
    }

    // ---- epilogue: C/D map col=lane&15, row=(lane>>4)*4+reg ----
    #pragma unroll
    for (int i = 0; i < 4; ++i) {
        int r0 = row0 + wr * 64 + i * 16 + (lane >> 4) * 4;
        #pragma unroll
        for (int jn = 0; jn < 4; ++jn) {
            int c = n0 + wc * 64 + jn * 16 + (lane & 15);
            #pragma unroll
            for (int rr = 0; rr < 4; ++rr) {
                int r = r0 + rr;
                if (r < N_ATOMS) H[(long long)r * HID + c] = f2bf(acc[i][jn][rr]);
            }
        }
    }
}

// ---------------- per-atom attention dots ----------------
__global__ __launch_bounds__(256) void dots_kernel(const bf16_t* __restrict__ H,
                                                   const float* __restrict__ a,
                                                   float* __restrict__ ss,
                                                   float* __restrict__ st) {
    int wave = threadIdx.x >> 6;
    int lane = threadIdx.x & 63;
    int atom = blockIdx.x * 4 + wave;
    if (atom >= N_ATOMS) return;
    float4 h4  = ld4(&H[(long long)atom * HID + lane * 4]);
    float4 as4 = *(const float4*)&a[lane * 4];
    float4 at4 = *(const float4*)&a[HID + lane * 4];
    float ps = h4.x * as4.x + h4.y * as4.y + h4.z * as4.z + h4.w * as4.w;
    float pt = h4.x * at4.x + h4.y * at4.y + h4.z * at4.z + h4.w * at4.w;
    #pragma unroll
    for (int o = 32; o > 0; o >>= 1) {
        ps += __shfl_xor(ps, o);
        pt += __shfl_xor(pt, o);
    }
    if (lane == 0) { ss[atom] = ps; st[atom] = pt; }
}

// ---------------- fused softmax-aggregate + residual + ELU (one wave per target) ----------------
__global__ __launch_bounds__(256) void aggregate(const bf16_t* __restrict__ H,
                                                 const float* __restrict__ ss,
                                                 const float* __restrict__ st,
                                                 const int* __restrict__ cnt,
                                                 const int* __restrict__ lst,
                                                 bf16_t* __restrict__ X,
                                                 int residual) {
    int wave = threadIdx.x >> 6;
    int lane = threadIdx.x & 63;
    int t = blockIdx.x * 4 + wave;
    if (t >= N_ATOMS) return;
    int n = cnt[t]; if (n > CAP) n = CAP;
    float stt = st[t];
    float ax = 0.f, ay = 0.f, az = 0.f, aw = 0.f;
    float denom = 0.f;
    for (int i = 0; i < n; ++i) {
        int s = lst[t * CAP + i];
        float e = ss[s] + stt;
        e = e > 0.f ? e : 0.2f * e;            // leaky_relu(0.2)
        float att = __expf(e);
        denom += att;
        float4 hv = ld4(&H[(long long)s * HID + lane * 4]);
        ax += att * hv.x; ay += att * hv.y; az += att * hv.z; aw += att * hv.w;
    }
    float inv = 1.f / (denom + 1e-8f);
    float rx = ax * inv, ry = ay * inv, rz = az * inv, rw = aw * inv;
    if (residual) {
        float4 xv = ld4(&X[(long long)t * HID + lane * 4]);
        rx += xv.x; ry += xv.y; rz += xv.z; rw += xv.w;
    }
    rx = rx > 0.f ? rx : (__expf(rx) - 1.f);   // elu(alpha=1)
    ry = ry > 0.f ? ry : (__expf(ry) - 1.f);
    rz = rz > 0.f ? rz : (__expf(rz) - 1.f);
    rw = rw > 0.f ? rw : (__expf(rw) - 1.f);
    st4(&X[(long long)t * HID + lane * 4], make_float4(rx, ry, rz, rw));
}

// ---------------- molecule mean pool (mol_ids int32, sorted) ----------------
__device__ inline int lower_bound_i(const int* a, int n, int v) {
    int lo = 0, hi = n;
    while (lo < hi) { int mid = (lo + hi) >> 1; if (a[mid] < v) lo = mid + 1; else hi = mid; }
    return lo;
}

__global__ __launch_bounds__(64) void pool_kernel(const bf16_t* __restrict__ X,
                                                  const int* __restrict__ mol,
                                                  float* __restrict__ out) {
    int m = blockIdx.x;
    int lane = threadIdx.x;
    int lo = lower_bound_i(mol, N_ATOMS, m);
    int hi = lower_bound_i(mol, N_ATOMS, m + 1);
    float ax = 0.f, ay = 0.f, az = 0.f, aw = 0.f;
    for (int i = lo; i < hi; ++i) {
        float4 v = ld4(&X[(long long)i * HID + lane * 4]);
        ax += v.x; ay += v.y; az += v.z; aw += v.w;
    }
    float c = (float)(hi - lo);
    float4 r = make_float4(0.f, 0.f, 0.f, 0.f);
    if (c > 0.f) {
        float inv = 1.f / c;
        r = make_float4(ax * inv, ay * inv, az * inv, aw * inv);
    }
    *(float4*)&out[(long long)m * HID + lane * 4] = r;
}

extern "C" void kernel_launch(void* const* d_in, const int* in_sizes, int n_in,
                              void* d_out, int out_size, void* d_ws, size_t ws_size,
                              hipStream_t stream) {
    const float* f_atoms = (const float*)d_in[0];
    const int*   ei      = (const int*)d_in[1];    // integer inputs are int32
    const int*   mol     = (const int*)d_in[2];
    const float* W0      = (const float*)d_in[3];
    const float* a0      = (const float*)d_in[4];
    const float* W1      = (const float*)d_in[5];
    const float* a1      = (const float*)d_in[6];
    const float* W2      = (const float*)d_in[7];
    const float* a2      = (const float*)d_in[8];
    float* out = (float*)d_out;

    // workspace layout (bf16 hidden states)
    char* ws = (char*)d_ws;
    size_t off = 0;
    bf16_t* X  = (bf16_t*)(ws + off); off += (size_t)N_ATOMS * HID * 2;   // 102.4 MB
    bf16_t* Hb = (bf16_t*)(ws + off); off += (size_t)N_ATOMS * HID * 2;   // 102.4 MB
    float* ss  = (float*)(ws + off);  off += (size_t)N_ATOMS * 4;
    float* st  = (float*)(ws + off);  off += (size_t)N_ATOMS * 4;
    int* cnt   = (int*)(ws + off);    off += (size_t)N_ATOMS * 4;
    int* lst   = (int*)(ws + off);    off += (size_t)N_ATOMS * CAP * 4;   // 25.6 MB
    if (ws_size < off) return;  // diagnostic: output left as-is (absmax ~1.297), no crash

    // transposed bf16 weights live in d_out's first 131KB; pool overwrites all of d_out at the end
    bf16_t* Wt = (bf16_t*)d_out;

    hipMemsetAsync(cnt, 0, (size_t)N_ATOMS * 4, stream);
    build_adj<<<(N_EDGES + 255) / 256, 256, 0, stream>>>(ei, cnt, lst);

    const dim3 gemm_grid((N_ATOMS + 127) / 128, 2);   // 1563 x 2
    const int  agg_blocks = N_ATOMS / 4;

    // ---- layer 0: A = f_atoms fp32, K=133 padded to 160 ----
    transpose_w<<<(HID * 160 + 255) / 256, 256, 0, stream>>>(W0, Wt, FDIM, 160);
    gemm_mfma<true, 5, FDIM><<<gemm_grid, 256, 0, stream>>>(f_atoms, Wt, Hb);
    dots_kernel<<<agg_blocks, 256, 0, stream>>>(Hb, a0, ss, st);
    aggregate<<<agg_blocks, 256, 0, stream>>>(Hb, ss, st, cnt, lst, X, 0);

    // ---- layer 1 ----
    transpose_w<<<(HID * HID + 255) / 256, 256, 0, stream>>>(W1, Wt, HID, HID);
    gemm_mfma<false, 8, HID><<<gemm_grid, 256, 0, stream>>>(X, Wt, Hb);
    dots_kernel<<<agg_blocks, 256, 0, stream>>>(Hb, a1, ss, st);
    aggregate<<<agg_blocks, 256, 0, stream>>>(Hb, ss, st, cnt, lst, X, 1);

    // ---- layer 2 ----
    transpose_w<<<(HID * HID + 255) / 256, 256, 0, stream>>>(W2, Wt, HID, HID);
    gemm_mfma<false, 8, HID><<<gemm_grid, 256, 0, stream>>>(X, Wt, Hb);
    dots_kernel<<<agg_blocks, 256, 0, stream>>>(Hb, a2, ss, st);
    aggregate<<<agg_blocks, 256, 0, stream>>>(Hb, ss, st, cnt, lst, X, 1);

    // ---- molecule mean pool (overwrites Wt scratch region too) ----
    pool_kernel<<<NMOLS, 64, 0, stream>>>(X, mol, out);
}

// Round 5
// 686.544 us; speedup vs baseline: 2.7880x; 1.1052x over previous
//
#include <hip/hip_runtime.h>

#define N_ATOMS 200000
#define N_EDGES 800000
#define FDIM    133
#define HID     256
#define NMOLS   8000
#define CAP     32   // Poisson(4) in-degree; P(deg>=32) ~ 1e-20

typedef unsigned short bf16_t;
typedef __attribute__((ext_vector_type(4))) float f32x4;
typedef __attribute__((ext_vector_type(8))) short bf16x8;

__device__ inline float bf2f(bf16_t u) {
    union { unsigned int i; float f; } v; v.i = ((unsigned int)u) << 16; return v.f;
}
__device__ inline bf16_t f2bf(float f) {
    union { float f; unsigned int i; } v; v.f = f;
    return (bf16_t)((v.i + 0x7fffu + ((v.i >> 16) & 1u)) >> 16);   // RNE
}
__device__ inline float4 ld4(const bf16_t* p) {
    ushort4 u = *(const ushort4*)p;
    return make_float4(bf2f(u.x), bf2f(u.y), bf2f(u.z), bf2f(u.w));
}
__device__ inline void st4(bf16_t* p, float4 v) {
    ushort4 u; u.x = f2bf(v.x); u.y = f2bf(v.y); u.z = f2bf(v.z); u.w = f2bf(v.w);
    *(ushort4*)p = u;
}

// async global->LDS, 16B per lane; lds dest is wave-uniform base (+lane*16 implicit)
__device__ inline void gload_lds16(const void* g, void* l) {
    __builtin_amdgcn_global_load_lds((const __attribute__((address_space(1))) unsigned int*)g,
                                     (__attribute__((address_space(3))) unsigned int*)l,
                                     16, 0, 0);
}

// ---------------- adjacency build (edge_index arrives as int32) ----------------
__global__ __launch_bounds__(256) void build_adj(const int* __restrict__ ei,
                                                 int* __restrict__ cnt,
                                                 int* __restrict__ lst) {
    int e = blockIdx.x * 256 + threadIdx.x;
    if (e >= N_EDGES) return;
    int s = ei[e];
    int t = ei[N_EDGES + e];
    int p = atomicAdd(&cnt[t], 1);
    if (p < CAP) lst[t * CAP + p] = s;
}

// ---------------- weight transpose+convert: Wt[n][k] = bf16(W[k][n]), zero-pad k>=K ----------------
__global__ __launch_bounds__(256) void transpose_w(const float* __restrict__ W,
                                                   bf16_t* __restrict__ Wt,
                                                   int K, int Kpad) {
    int idx = blockIdx.x * 256 + threadIdx.x;
    if (idx >= HID * Kpad) return;
    int n = idx / Kpad, k = idx - n * Kpad;
    Wt[idx] = (k < K) ? f2bf(W[k * HID + n]) : (bf16_t)0;
}

// ---------------- MFMA GEMM: H[M x 256] = A[M x K] @ W, W transposed bf16 Wt[256][Kpad] ----
// 128x128 tile, 4 waves (2x2), BK=32, mfma_f32_16x16x32_bf16, 4x4 frags/wave.
template <bool A_FP32, int KSTEPS, int LDA>
__global__ __launch_bounds__(256) void gemm_mfma(const void* __restrict__ Av,
                                                 const bf16_t* __restrict__ Wt,
                                                 bf16_t* __restrict__ H) {
    __shared__ bf16_t As[128][32];   // 8KB
    __shared__ bf16_t Bs[128][32];   // 8KB
    const int tid  = threadIdx.x;
    const int lane = tid & 63;
    const int w    = tid >> 6;
    const int wr   = w >> 1, wc = w & 1;
    const int row0 = blockIdx.x * 128;
    const int n0   = blockIdx.y * 128;
    const int KP   = KSTEPS * 32;

    f32x4 acc[4][4] = {};

    #pragma unroll
    for (int ks = 0; ks < KSTEPS; ++ks) {
        const int k0 = ks * 32;
        if (ks) __syncthreads();

        if constexpr (A_FP32) {
            const float* A = (const float*)Av;
            int r  = tid >> 1;
            int kh = (tid & 1) * 16;
            int grow = row0 + r; if (grow >= N_ATOMS) grow = N_ATOMS - 1;
            const float* src = A + (long long)grow * LDA + k0 + kh;
            short v[16];
            #pragma unroll
            for (int j = 0; j < 16; ++j) {
                int gk = k0 + kh + j;
                v[j] = (gk < LDA) ? (short)f2bf(src[j]) : (short)0;
            }
            *(bf16x8*)&As[r][kh]     = *(bf16x8*)&v[0];
            *(bf16x8*)&As[r][kh + 8] = *(bf16x8*)&v[8];
        } else {
            const bf16_t* A = (const bf16_t*)Av;
            #pragma unroll
            for (int j = 0; j < 2; ++j) {
                int u  = j * 4096 + w * 1024 + lane * 16;
                int r  = u >> 6;
                int cb = u & 63;
                int grow = row0 + r; if (grow >= N_ATOMS) grow = N_ATOMS - 1;
                const bf16_t* src = A + (long long)grow * LDA + k0 + (cb >> 1);
                gload_lds16(src, (char*)&As[0][0] + j * 4096 + w * 1024);
            }
        }
        #pragma unroll
        for (int j = 0; j < 2; ++j) {
            int u  = j * 4096 + w * 1024 + lane * 16;
            int r  = u >> 6;
            int cb = u & 63;
            const bf16_t* src = Wt + (long long)(n0 + r) * KP + k0 + (cb >> 1);
            gload_lds16(src, (char*)&Bs[0][0] + j * 4096 + w * 1024);
        }
        __syncthreads();

        const int fr   = lane & 15;
        const int koff = (lane >> 4) * 8;
        bf16x8 af[4], bfr[4];
        #pragma unroll
        for (int i = 0; i < 4; ++i)
            af[i] = *(const bf16x8*)&As[wr * 64 + i * 16 + fr][koff];
        #pragma unroll
        for (int jn = 0; jn < 4; ++jn)
            bfr[jn] = *(const bf16x8*)&Bs[wc * 64 + jn * 16 + fr][koff];
        #pragma unroll
        for (int i = 0; i < 4; ++i)
            #pragma unroll
            for (int jn = 0; jn < 4; ++jn)
                acc[i][jn] = __builtin_amdgcn_mfma_f32_16x16x32_bf16(af[i], bfr[jn], acc[i][jn], 0, 0, 0);
    }

    #pragma unroll
    for (int i = 0; i < 4; ++i) {
        int r0 = row0 + wr * 64 + i * 16 + (lane >> 4) * 4;
        #pragma unroll
        for (int jn = 0; jn < 4; ++jn) {
            int c = n0 + wc * 64 + jn * 16 + (lane & 15);
            #pragma unroll
            for (int rr = 0; rr < 4; ++rr) {
                int r = r0 + rr;
                if (r < N_ATOMS) H[(long long)r * HID + c] = f2bf(acc[i][jn][rr]);
            }
        }
    }
}

// ---------------- per-atom attention dots ----------------
__global__ __launch_bounds__(256) void dots_kernel(const bf16_t* __restrict__ H,
                                                   const float* __restrict__ a,
                                                   float* __restrict__ ss,
                                                   float* __restrict__ st) {
    int wave = threadIdx.x >> 6;
    int lane = threadIdx.x & 63;
    int atom = blockIdx.x * 4 + wave;
    if (atom >= N_ATOMS) return;
    float4 h4  = ld4(&H[(long long)atom * HID + lane * 4]);
    float4 as4 = *(const float4*)&a[lane * 4];
    float4 at4 = *(const float4*)&a[HID + lane * 4];
    float ps = h4.x * as4.x + h4.y * as4.y + h4.z * as4.z + h4.w * as4.w;
    float pt = h4.x * at4.x + h4.y * at4.y + h4.z * at4.z + h4.w * at4.w;
    #pragma unroll
    for (int o = 32; o > 0; o >>= 1) {
        ps += __shfl_xor(ps, o);
        pt += __shfl_xor(pt, o);
    }
    if (lane == 0) { ss[atom] = ps; st[atom] = pt; }
}

// ---------------- fused softmax-aggregate + residual + ELU ----------------
// One wave per target; edges processed in chunks of 4 so the 4 ss-gathers and
// 4 H-row gathers are independent (4 outstanding vmem each) instead of a
// serial load->use chain per edge.  lst rows are 128B-aligned (CAP=32 ints),
// so the int4 index load is always in-bounds; entries beyond n are poison and
// are clamped to t (load target's own row, weight 0) to stay memory-safe.
__global__ __launch_bounds__(256) void aggregate(const bf16_t* __restrict__ H,
                                                 const float* __restrict__ ss,
                                                 const float* __restrict__ st,
                                                 const int* __restrict__ cnt,
                                                 const int* __restrict__ lst,
                                                 bf16_t* __restrict__ X,
                                                 int residual) {
    int wave = threadIdx.x >> 6;
    int lane = threadIdx.x & 63;
    int t = blockIdx.x * 4 + wave;
    if (t >= N_ATOMS) return;
    int n = cnt[t]; if (n > CAP) n = CAP;
    float stt = st[t];
    const int base = t * CAP;

    float ax = 0.f, ay = 0.f, az = 0.f, aw = 0.f;
    float denom = 0.f;

    for (int i0 = 0; i0 < n; i0 += 4) {
        int4 s4 = *(const int4*)&lst[base + i0];
        int s0 = (i0 + 0 < n) ? s4.x : t;
        int s1 = (i0 + 1 < n) ? s4.y : t;
        int s2 = (i0 + 2 < n) ? s4.z : t;
        int s3 = (i0 + 3 < n) ? s4.w : t;

        float v0 = ss[s0], v1 = ss[s1], v2 = ss[s2], v3 = ss[s3];

        float e0 = v0 + stt; e0 = e0 > 0.f ? e0 : 0.2f * e0;
        float e1 = v1 + stt; e1 = e1 > 0.f ? e1 : 0.2f * e1;
        float e2 = v2 + stt; e2 = e2 > 0.f ? e2 : 0.2f * e2;
        float e3 = v3 + stt; e3 = e3 > 0.f ? e3 : 0.2f * e3;

        float t0 = (i0 + 0 < n) ? __expf(e0) : 0.f;
        float t1 = (i0 + 1 < n) ? __expf(e1) : 0.f;
        float t2 = (i0 + 2 < n) ? __expf(e2) : 0.f;
        float t3 = (i0 + 3 < n) ? __expf(e3) : 0.f;

        float4 h0 = ld4(&H[(long long)s0 * HID + lane * 4]);
        float4 h1 = ld4(&H[(long long)s1 * HID + lane * 4]);
        float4 h2 = ld4(&H[(long long)s2 * HID + lane * 4]);
        float4 h3 = ld4(&H[(long long)s3 * HID + lane * 4]);

        denom += (t0 + t1) + (t2 + t3);
        ax += t0 * h0.x + t1 * h1.x + t2 * h2.x + t3 * h3.x;
        ay += t0 * h0.y + t1 * h1.y + t2 * h2.y + t3 * h3.y;
        az += t0 * h0.z + t1 * h1.z + t2 * h2.z + t3 * h3.z;
        aw += t0 * h0.w + t1 * h1.w + t2 * h2.w + t3 * h3.w;
    }

    float inv = 1.f / (denom + 1e-8f);
    float rx = ax * inv, ry = ay * inv, rz = az * inv, rw = aw * inv;
    if (residual) {
        float4 xv = ld4(&X[(long long)t * HID + lane * 4]);
        rx += xv.x; ry += xv.y; rz += xv.z; rw += xv.w;
    }
    rx = rx > 0.f ? rx : (__expf(rx) - 1.f);   // elu(alpha=1)
    ry = ry > 0.f ? ry : (__expf(ry) - 1.f);
    rz = rz > 0.f ? rz : (__expf(rz) - 1.f);
    rw = rw > 0.f ? rw : (__expf(rw) - 1.f);
    st4(&X[(long long)t * HID + lane * 4], make_float4(rx, ry, rz, rw));
}

// ---------------- molecule mean pool (mol_ids int32, sorted) ----------------
__device__ inline int lower_bound_i(const int* a, int n, int v) {
    int lo = 0, hi = n;
    while (lo < hi) { int mid = (lo + hi) >> 1; if (a[mid] < v) lo = mid + 1; else hi = mid; }
    return lo;
}

__global__ __launch_bounds__(64) void pool_kernel(const bf16_t* __restrict__ X,
                                                  const int* __restrict__ mol,
                                                  float* __restrict__ out) {
    int m = blockIdx.x;
    int lane = threadIdx.x;
    int lo = lower_bound_i(mol, N_ATOMS, m);
    int hi = lower_bound_i(mol, N_ATOMS, m + 1);
    float ax = 0.f, ay = 0.f, az = 0.f, aw = 0.f;
    for (int i = lo; i < hi; ++i) {
        float4 v = ld4(&X[(long long)i * HID + lane * 4]);
        ax += v.x; ay += v.y; az += v.z; aw += v.w;
    }
    float c = (float)(hi - lo);
    float4 r = make_float4(0.f, 0.f, 0.f, 0.f);
    if (c > 0.f) {
        float inv = 1.f / c;
        r = make_float4(ax * inv, ay * inv, az * inv, aw * inv);
    }
    *(float4*)&out[(long long)m * HID + lane * 4] = r;
}

extern "C" void kernel_launch(void* const* d_in, const int* in_sizes, int n_in,
                              void* d_out, int out_size, void* d_ws, size_t ws_size,
                              hipStream_t stream) {
    const float* f_atoms = (const float*)d_in[0];
    const int*   ei      = (const int*)d_in[1];
    const int*   mol     = (const int*)d_in[2];
    const float* W0      = (const float*)d_in[3];
    const float* a0      = (const float*)d_in[4];
    const float* W1      = (const float*)d_in[5];
    const float* a1      = (const float*)d_in[6];
    const float* W2      = (const float*)d_in[7];
    const float* a2      = (const float*)d_in[8];
    float* out = (float*)d_out;

    char* ws = (char*)d_ws;
    size_t off = 0;
    bf16_t* X  = (bf16_t*)(ws + off); off += (size_t)N_ATOMS * HID * 2;   // 102.4 MB
    bf16_t* Hb = (bf16_t*)(ws + off); off += (size_t)N_ATOMS * HID * 2;   // 102.4 MB
    float* ss  = (float*)(ws + off);  off += (size_t)N_ATOMS * 4;
    float* st  = (float*)(ws + off);  off += (size_t)N_ATOMS * 4;
    int* cnt   = (int*)(ws + off);    off += (size_t)N_ATOMS * 4;
    int* lst   = (int*)(ws + off);    off += (size_t)N_ATOMS * CAP * 4;   // 25.6 MB
    if (ws_size < off) return;

    bf16_t* Wt = (bf16_t*)d_out;   // 131KB scratch; pool overwrites all of d_out at the end

    hipMemsetAsync(cnt, 0, (size_t)N_ATOMS * 4, stream);
    build_adj<<<(N_EDGES + 255) / 256, 256, 0, stream>>>(ei, cnt, lst);

    const dim3 gemm_grid((N_ATOMS + 127) / 128, 2);
    const int  agg_blocks = N_ATOMS / 4;

    // ---- layer 0: A = f_atoms fp32, K=133 padded to 160 ----
    transpose_w<<<(HID * 160 + 255) / 256, 256, 0, stream>>>(W0, Wt, FDIM, 160);
    gemm_mfma<true, 5, FDIM><<<gemm_grid, 256, 0, stream>>>(f_atoms, Wt, Hb);
    dots_kernel<<<agg_blocks, 256, 0, stream>>>(Hb, a0, ss, st);
    aggregate<<<agg_blocks, 256, 0, stream>>>(Hb, ss, st, cnt, lst, X, 0);

    // ---- layer 1 ----
    transpose_w<<<(HID * HID + 255) / 256, 256, 0, stream>>>(W1, Wt, HID, HID);
    gemm_mfma<false, 8, HID><<<gemm_grid, 256, 0, stream>>>(X, Wt, Hb);
    dots_kernel<<<agg_blocks, 256, 0, stream>>>(Hb, a1, ss, st);
    aggregate<<<agg_blocks, 256, 0, stream>>>(Hb, ss, st, cnt, lst, X, 1);

    // ---- layer 2 ----
    transpose_w<<<(HID * HID + 255) / 256, 256, 0, stream>>>(W2, Wt, HID, HID);
    gemm_mfma<false, 8, HID><<<gemm_grid, 256, 0, stream>>>(X, Wt, Hb);
    dots_kernel<<<agg_blocks, 256, 0, stream>>>(Hb, a2, ss, st);
    aggregate<<<agg_blocks, 256, 0, stream>>>(Hb, ss, st, cnt, lst, X, 1);

    pool_kernel<<<NMOLS, 64, 0, stream>>>(X, mol, out);
}

// Round 7
// 666.717 us; speedup vs baseline: 2.8710x; 1.0297x over previous
//
#include <hip/hip_runtime.h>

#define N_ATOMS 200000
#define N_EDGES 800000
#define FDIM    133
#define HID     256
#define NMOLS   8000
#define CAP     32   // Poisson(4) in-degree; P(deg>=32) ~ 1e-20

typedef unsigned short bf16_t;
typedef __attribute__((ext_vector_type(4))) float f32x4;
typedef __attribute__((ext_vector_type(8))) short bf16x8;

__device__ inline float bf2f(bf16_t u) {
    union { unsigned int i; float f; } v; v.i = ((unsigned int)u) << 16; return v.f;
}
__device__ inline bf16_t f2bf(float f) {
    union { float f; unsigned int i; } v; v.f = f;
    return (bf16_t)((v.i + 0x7fffu + ((v.i >> 16) & 1u)) >> 16);   // RNE
}
__device__ inline float4 ld4(const bf16_t* p) {
    ushort4 u = *(const ushort4*)p;
    return make_float4(bf2f(u.x), bf2f(u.y), bf2f(u.z), bf2f(u.w));
}
__device__ inline void st4(bf16_t* p, float4 v) {
    ushort4 u; u.x = f2bf(v.x); u.y = f2bf(v.y); u.z = f2bf(v.z); u.w = f2bf(v.w);
    *(ushort4*)p = u;
}

// async global->LDS, 16B/lane; lds dest is wave-uniform base (+lane*16 implicit)
__device__ inline void gload_lds16(const void* g, void* l) {
    __builtin_amdgcn_global_load_lds((const __attribute__((address_space(1))) unsigned int*)g,
                                     (__attribute__((address_space(3))) unsigned int*)l,
                                     16, 0, 0);
}

// ---------------- adjacency build (edge_index arrives as int32) ----------------
__global__ __launch_bounds__(256) void build_adj(const int* __restrict__ ei,
                                                 int* __restrict__ cnt,
                                                 int* __restrict__ lst) {
    int e = blockIdx.x * 256 + threadIdx.x;
    if (e >= N_EDGES) return;
    int s = ei[e];
    int t = ei[N_EDGES + e];
    int p = atomicAdd(&cnt[t], 1);
    if (p < CAP) lst[t * CAP + p] = s;
}

// ---------------- weight transpose+convert: Wt[n][k] = bf16(W[k][n]), zero-pad k>=K ----------------
__global__ __launch_bounds__(256) void transpose_w(const float* __restrict__ W,
                                                   bf16_t* __restrict__ Wt,
                                                   int K, int Kpad) {
    int idx = blockIdx.x * 256 + threadIdx.x;
    if (idx >= HID * Kpad) return;
    int n = idx / Kpad, k = idx - n * Kpad;
    Wt[idx] = (k < K) ? f2bf(W[k * HID + n]) : (bf16_t)0;
}

// ---------------- MFMA GEMM + fused attention-dot partials ----------------
// H[M x 256] = A[M x K] @ W (Wt[256][Kpad] transposed bf16).
// 128x128 tile, 4 waves (2x2), BK=32, double-buffered LDS, one barrier/K-step.
// Epilogue computes per-row dot partials over this wave's 64 columns and
// writes them to slot (blockIdx.y*2 + wc) -- one writer per slot, no races.
template <bool A_FP32, int KSTEPS, int LDA>
__global__ __launch_bounds__(256) void gemm_mfma(const void* __restrict__ Av,
                                                 const bf16_t* __restrict__ Wt,
                                                 bf16_t* __restrict__ H,
                                                 const float* __restrict__ avec,
                                                 float* __restrict__ ssp,
                                                 float* __restrict__ stp) {
    __shared__ bf16_t As[2][128][32];   // 2 x 8KB
    __shared__ bf16_t Bs[2][128][32];   // 2 x 8KB
    const int tid  = threadIdx.x;
    const int lane = tid & 63;
    const int w    = tid >> 6;
    const int wr   = w >> 1, wc = w & 1;
    const int row0 = blockIdx.x * 128;
    const int n0   = blockIdx.y * 128;
    const int KP   = KSTEPS * 32;

    // one partial slot per (column-block, column-wave): 4 slots total
    const long long slot = (long long)(blockIdx.y * 2 + wc) * N_ATOMS;
    ssp += slot;
    stp += slot;

    // fp32-A staging registers (layer 0): row sr, k-half skh
    float sreg[16];
    const int sr  = tid >> 1;
    const int skh = (tid & 1) * 16;
    int sgrow = row0 + sr; if (sgrow >= N_ATOMS) sgrow = N_ATOMS - 1;

#define ISSUE(ks_, buf_) do {                                                          \
    const int k0_ = (ks_) * 32;                                                        \
    if constexpr (A_FP32) {                                                            \
        _Pragma("unroll")                                                              \
        for (int j = 0; j < 16; ++j) {                                                 \
            int gk = k0_ + skh + j;                                                    \
            sreg[j] = (gk < LDA) ? ((const float*)Av)[(long long)sgrow * LDA + gk] : 0.f; \
        }                                                                              \
    } else {                                                                           \
        _Pragma("unroll")                                                              \
        for (int j = 0; j < 2; ++j) {                                                  \
            int u = j * 4096 + w * 1024 + lane * 16;                                   \
            int r = u >> 6, cb = u & 63;                                               \
            int grow = row0 + r; if (grow >= N_ATOMS) grow = N_ATOMS - 1;              \
            gload_lds16((const bf16_t*)Av + (long long)grow * LDA + k0_ + (cb >> 1),   \
                        (char*)&As[buf_][0][0] + j * 4096 + w * 1024);                 \
        }                                                                              \
    }                                                                                  \
    _Pragma("unroll")                                                                  \
    for (int j = 0; j < 2; ++j) {                                                      \
        int u = j * 4096 + w * 1024 + lane * 16;                                       \
        int r = u >> 6, cb = u & 63;                                                   \
        gload_lds16(Wt + (long long)(n0 + r) * KP + k0_ + (cb >> 1),                   \
                    (char*)&Bs[buf_][0][0] + j * 4096 + w * 1024);                     \
    }                                                                                  \
} while (0)

#define COMMIT(buf_) do {                                                              \
    if constexpr (A_FP32) {                                                            \
        short v_[16];                                                                  \
        _Pragma("unroll")                                                              \
        for (int j = 0; j < 16; ++j) v_[j] = (short)f2bf(sreg[j]);                     \
        *(bf16x8*)&As[buf_][sr][skh]     = *(bf16x8*)&v_[0];                           \
        *(bf16x8*)&As[buf_][sr][skh + 8] = *(bf16x8*)&v_[8];                           \
    }                                                                                  \
} while (0)

    f32x4 acc[4][4] = {};

    // prologue: stage tile 0 into buf 0
    ISSUE(0, 0);
    COMMIT(0);
    __syncthreads();          // drains vmcnt(0)+lgkmcnt(0): tile 0 resident

    int buf = 0;
    #pragma unroll
    for (int ks = 0; ks < KSTEPS; ++ks) {
        if (ks + 1 < KSTEPS) ISSUE(ks + 1, buf ^ 1);   // prefetch next tile (async)

        const int fr   = lane & 15;
        const int koff = (lane >> 4) * 8;
        bf16x8 af[4], bfr[4];
        #pragma unroll
        for (int i = 0; i < 4; ++i)
            af[i] = *(const bf16x8*)&As[buf][wr * 64 + i * 16 + fr][koff];
        #pragma unroll
        for (int jn = 0; jn < 4; ++jn)
            bfr[jn] = *(const bf16x8*)&Bs[buf][wc * 64 + jn * 16 + fr][koff];
        #pragma unroll
        for (int i = 0; i < 4; ++i)
            #pragma unroll
            for (int jn = 0; jn < 4; ++jn)
                acc[i][jn] = __builtin_amdgcn_mfma_f32_16x16x32_bf16(af[i], bfr[jn], acc[i][jn], 0, 0, 0);

        if (ks + 1 < KSTEPS) COMMIT(buf ^ 1);          // fp32 path: reg->LDS after compute
        __syncthreads();       // completes prefetch (vmcnt drain) + orders buffer reuse
        buf ^= 1;
    }
#undef ISSUE
#undef COMMIT

    // ---- epilogue: H store (bf16) + fused dot partials from fp32 acc ----
    float as_v[4], at_v[4];
    #pragma unroll
    for (int jn = 0; jn < 4; ++jn) {
        int c = n0 + wc * 64 + jn * 16 + (lane & 15);
        as_v[jn] = avec[c];
        at_v[jn] = avec[HID + c];
    }
    #pragma unroll
    for (int i = 0; i < 4; ++i) {
        #pragma unroll
        for (int rr = 0; rr < 4; ++rr) {
            int r = row0 + wr * 64 + i * 16 + (lane >> 4) * 4 + rr;
            float ps = 0.f, pt = 0.f;
            #pragma unroll
            for (int jn = 0; jn < 4; ++jn) {
                float h = acc[i][jn][rr];
                ps += h * as_v[jn];
                pt += h * at_v[jn];
                if (r < N_ATOMS)
                    H[(long long)r * HID + (n0 + wc * 64 + jn * 16 + (lane & 15))] = f2bf(h);
            }
            #pragma unroll
            for (int o = 1; o < 16; o <<= 1) {   // reduce over the 16 column-lanes
                ps += __shfl_xor(ps, o);
                pt += __shfl_xor(pt, o);
            }
            if ((lane & 15) == 0 && r < N_ATOMS) {
                ssp[r] = ps;    // unique writer: slot (blockIdx.y*2+wc), row r
                stp[r] = pt;
            }
        }
    }
}

// ---------------- combine the 4 per-slot dot partials ----------------
__global__ __launch_bounds__(256) void combine_dots(const float* __restrict__ ssp,
                                                    const float* __restrict__ stp,
                                                    float* __restrict__ ss,
                                                    float* __restrict__ st) {
    int i = blockIdx.x * 256 + threadIdx.x;
    if (i >= N_ATOMS) return;
    ss[i] = (ssp[i] + ssp[N_ATOMS + i]) + (ssp[2 * N_ATOMS + i] + ssp[3 * N_ATOMS + i]);
    st[i] = (stp[i] + stp[N_ATOMS + i]) + (stp[2 * N_ATOMS + i] + stp[3 * N_ATOMS + i]);
}

// ---------------- fused softmax-aggregate + residual + ELU ----------------
// One wave per target; edges in chunks of 4 -> 4 independent gathers in flight.
__global__ __launch_bounds__(256) void aggregate(const bf16_t* __restrict__ H,
                                                 const float* __restrict__ ss,
                                                 const float* __restrict__ st,
                                                 const int* __restrict__ cnt,
                                                 const int* __restrict__ lst,
                                                 bf16_t* __restrict__ X,
                                                 int residual) {
    int wave = threadIdx.x >> 6;
    int lane = threadIdx.x & 63;
    int t = blockIdx.x * 4 + wave;
    if (t >= N_ATOMS) return;
    int n = cnt[t]; if (n > CAP) n = CAP;
    float stt = st[t];
    const int base = t * CAP;

    float ax = 0.f, ay = 0.f, az = 0.f, aw = 0.f;
    float denom = 0.f;

    for (int i0 = 0; i0 < n; i0 += 4) {
        int4 s4 = *(const int4*)&lst[base + i0];
        int s0 = (i0 + 0 < n) ? s4.x : t;
        int s1 = (i0 + 1 < n) ? s4.y : t;
        int s2 = (i0 + 2 < n) ? s4.z : t;
        int s3 = (i0 + 3 < n) ? s4.w : t;

        float v0 = ss[s0], v1 = ss[s1], v2 = ss[s2], v3 = ss[s3];

        float e0 = v0 + stt; e0 = e0 > 0.f ? e0 : 0.2f * e0;
        float e1 = v1 + stt; e1 = e1 > 0.f ? e1 : 0.2f * e1;
        float e2 = v2 + stt; e2 = e2 > 0.f ? e2 : 0.2f * e2;
        float e3 = v3 + stt; e3 = e3 > 0.f ? e3 : 0.2f * e3;

        float t0 = (i0 + 0 < n) ? __expf(e0) : 0.f;
        float t1 = (i0 + 1 < n) ? __expf(e1) : 0.f;
        float t2 = (i0 + 2 < n) ? __expf(e2) : 0.f;
        float t3 = (i0 + 3 < n) ? __expf(e3) : 0.f;

        float4 h0 = ld4(&H[(long long)s0 * HID + lane * 4]);
        float4 h1 = ld4(&H[(long long)s1 * HID + lane * 4]);
        float4 h2 = ld4(&H[(long long)s2 * HID + lane * 4]);
        float4 h3 = ld4(&H[(long long)s3 * HID + lane * 4]);

        denom += (t0 + t1) + (t2 + t3);
        ax += t0 * h0.x + t1 * h1.x + t2 * h2.x + t3 * h3.x;
        ay += t0 * h0.y + t1 * h1.y + t2 * h2.y + t3 * h3.y;
        az += t0 * h0.z + t1 * h1.z + t2 * h2.z + t3 * h3.z;
        aw += t0 * h0.w + t1 * h1.w + t2 * h2.w + t3 * h3.w;
    }

    float inv = 1.f / (denom + 1e-8f);
    float rx = ax * inv, ry = ay * inv, rz = az * inv, rw = aw * inv;
    if (residual) {
        float4 xv = ld4(&X[(long long)t * HID + lane * 4]);
        rx += xv.x; ry += xv.y; rz += xv.z; rw += xv.w;
    }
    rx = rx > 0.f ? rx : (__expf(rx) - 1.f);   // elu(alpha=1)
    ry = ry > 0.f ? ry : (__expf(ry) - 1.f);
    rz = rz > 0.f ? rz : (__expf(rz) - 1.f);
    rw = rw > 0.f ? rw : (__expf(rw) - 1.f);
    st4(&X[(long long)t * HID + lane * 4], make_float4(rx, ry, rz, rw));
}

// ---------------- molecule mean pool (mol_ids int32, sorted) ----------------
__device__ inline int lower_bound_i(const int* a, int n, int v) {
    int lo = 0, hi = n;
    while (lo < hi) { int mid = (lo + hi) >> 1; if (a[mid] < v) lo = mid + 1; else hi = mid; }
    return lo;
}

__global__ __launch_bounds__(64) void pool_kernel(const bf16_t* __restrict__ X,
                                                  const int* __restrict__ mol,
                                                  float* __restrict__ out) {
    int m = blockIdx.x;
    int lane = threadIdx.x;
    int lo = lower_bound_i(mol, N_ATOMS, m);
    int hi = lower_bound_i(mol, N_ATOMS, m + 1);
    float ax = 0.f, ay = 0.f, az = 0.f, aw = 0.f;
    for (int i = lo; i < hi; ++i) {
        float4 v = ld4(&X[(long long)i * HID + lane * 4]);
        ax += v.x; ay += v.y; az += v.z; aw += v.w;
    }
    float c = (float)(hi - lo);
    float4 r = make_float4(0.f, 0.f, 0.f, 0.f);
    if (c > 0.f) {
        float inv = 1.f / c;
        r = make_float4(ax * inv, ay * inv, az * inv, aw * inv);
    }
    *(float4*)&out[(long long)m * HID + lane * 4] = r;
}

extern "C" void kernel_launch(void* const* d_in, const int* in_sizes, int n_in,
                              void* d_out, int out_size, void* d_ws, size_t ws_size,
                              hipStream_t stream) {
    const float* f_atoms = (const float*)d_in[0];
    const int*   ei      = (const int*)d_in[1];
    const int*   mol     = (const int*)d_in[2];
    const float* W0      = (const float*)d_in[3];
    const float* a0      = (const float*)d_in[4];
    const float* W1      = (const float*)d_in[5];
    const float* a1      = (const float*)d_in[6];
    const float* W2      = (const float*)d_in[7];
    const float* a2      = (const float*)d_in[8];
    float* out = (float*)d_out;

    char* ws = (char*)d_ws;
    size_t off = 0;
    bf16_t* X  = (bf16_t*)(ws + off); off += (size_t)N_ATOMS * HID * 2;   // 102.4 MB
    bf16_t* Hb = (bf16_t*)(ws + off); off += (size_t)N_ATOMS * HID * 2;   // 102.4 MB
    float* ss  = (float*)(ws + off);  off += (size_t)N_ATOMS * 4;
    float* st  = (float*)(ws + off);  off += (size_t)N_ATOMS * 4;
    int* cnt   = (int*)(ws + off);    off += (size_t)N_ATOMS * 4;
    int* lst   = (int*)(ws + off);    off += (size_t)N_ATOMS * CAP * 4;   // 25.6 MB
    if (ws_size < off) return;

    // scratch carved from d_out (8.19 MB): Wt 131KB + 4-slot ssp/stp (3.2MB each).
    // pool_kernel overwrites ALL of d_out at the end.
    char* ob = (char*)d_out;
    bf16_t* Wt  = (bf16_t*)ob;                          // 131072 B
    float*  ssp = (float*)(ob + 131072);                // 4 x N_ATOMS f32 = 3.2 MB
    float*  stp = (float*)(ob + 131072 + 3200000);      // 4 x N_ATOMS f32 = 3.2 MB

    hipMemsetAsync(cnt, 0, (size_t)N_ATOMS * 4, stream);
    build_adj<<<(N_EDGES + 255) / 256, 256, 0, stream>>>(ei, cnt, lst);

    const dim3 gemm_grid((N_ATOMS + 127) / 128, 2);
    const int  agg_blocks = N_ATOMS / 4;
    const int  cmb_blocks = (N_ATOMS + 255) / 256;

    // ---- layer 0: A = f_atoms fp32, K=133 padded to 160 ----
    transpose_w<<<(HID * 160 + 255) / 256, 256, 0, stream>>>(W0, Wt, FDIM, 160);
    gemm_mfma<true, 5, FDIM><<<gemm_grid, 256, 0, stream>>>(f_atoms, Wt, Hb, a0, ssp, stp);
    combine_dots<<<cmb_blocks, 256, 0, stream>>>(ssp, stp, ss, st);
    aggregate<<<agg_blocks, 256, 0, stream>>>(Hb, ss, st, cnt, lst, X, 0);

    // ---- layer 1 ----
    transpose_w<<<(HID * HID + 255) / 256, 256, 0, stream>>>(W1, Wt, HID, HID);
    gemm_mfma<false, 8, HID><<<gemm_grid, 256, 0, stream>>>(X, Wt, Hb, a1, ssp, stp);
    combine_dots<<<cmb_blocks, 256, 0, stream>>>(ssp, stp, ss, st);
    aggregate<<<agg_blocks, 256, 0, stream>>>(Hb, ss, st, cnt, lst, X, 1);

    // ---- layer 2 ----
    transpose_w<<<(HID * HID + 255) / 256, 256, 0, stream>>>(W2, Wt, HID, HID);
    gemm_mfma<false, 8, HID><<<gemm_grid, 256, 0, stream>>>(X, Wt, Hb, a2, ssp, stp);
    combine_dots<<<cmb_blocks, 256, 0, stream>>>(ssp, stp, ss, st);
    aggregate<<<agg_blocks, 256, 0, stream>>>(Hb, ss, st, cnt, lst, X, 1);

    pool_kernel<<<NMOLS, 64, 0, stream>>>(X, mol, out);
}